// Round 9
// baseline (1285.321 us; speedup 1.0000x reference)
//
#include <hip/hip_runtime.h>
#include <math.h>

// Shapes (fixed by setup_inputs)
#define BATCH 8
#define TSEQ 2048
#define CIN 3
#define WIN 5
#define LSEQ 2044          // T - WIN + 1
#define LH 2045            // LSEQ + 1 (cls token appended)
#define DIM 128
#define DEPTH 4
#define DIN 256            // d_inner
#define NH 4               // heads
#define PDIM 64            // headdim
#define NSTATE 64          // d_state
#define CONVD 384          // d_inner + 2*d_state
#define DPROJ 644          // 2*d_inner + 2*d_state + nheads
#define QC 64              // chunk length
#define NCH 32             // number of chunks (32*64 = 2048 >= 2045)
#define LDP 68             // padded LDS row stride (17 float4s; bank-spread)
#define FTR 32             // tokens per k_front block

__device__ __forceinline__ float sigmoidf_(float x){ return 1.f/(1.f+__expf(-x)); }
__device__ __forceinline__ float siluf_(float x){ return x*sigmoidf_(x); }

// Fused causal dwconv+silu for channel q (in [0,384)) at token l of batch b.
// xBC channel q lives at zx column DIN+q.
__device__ __forceinline__ float convch(const float* __restrict__ zx,
                                        const float* __restrict__ cw,
                                        const float* __restrict__ cb,
                                        int b, int l, int q) {
  float a = cb[q];
  const float* w = cw + q*4;
#pragma unroll
  for (int k = 0; k < 4; ++k) {
    int tin = l - 3 + k;
    if (tin >= 0) a += zx[((size_t)b*LH + tin)*DPROJ + DIN + q] * w[k];
  }
  return siluf_(a);
}

// ---------------------------------------------------------------- weight transpose
__global__ void __launch_bounds__(256) k_transpose(
    const float* __restrict__ src, float* __restrict__ dst, int R, int C) {
  __shared__ float tile[64][65];
  const float* s = src + (size_t)blockIdx.z*R*C;
  float* d = dst + (size_t)blockIdx.z*R*C;
  int r0 = blockIdx.y*64, c0 = blockIdx.x*64;
  int tx = threadIdx.x & 63, ty = threadIdx.x >> 6;
  for (int rr = ty; rr < 64; rr += 4) {
    int r = r0 + rr, c = c0 + tx;
    if (r < R && c < C) tile[rr][tx] = s[(size_t)r*C + c];
  }
  __syncthreads();
  for (int cc = ty; cc < 64; cc += 4) {
    int c = c0 + cc, r = r0 + tx;
    if (c < C && r < R) d[(size_t)c*R + r] = tile[tx][cc];
  }
}

// ---------------------------------------------------------------- front MLP
__global__ void __launch_bounds__(256) k_front(
    const float* __restrict__ x, const float* __restrict__ w1,
    const float* __restrict__ b1, const float* __restrict__ w2,
    const float* __restrict__ b2, const float* __restrict__ cls,
    float* __restrict__ h) {
  int t = threadIdx.x;
  if (blockIdx.x == BATCH*64) {              // cls rows
    if (t < DIM) {
      float cv = cls[t];
      for (int b = 0; b < BATCH; ++b) h[((size_t)b*LH + LSEQ)*DIM + t] = cv;
    }
    return;
  }
  int b = blockIdx.x >> 6;
  int c0 = (blockIdx.x & 63) * FTR;
  __shared__ float xs[(FTR+4)*CIN];                  // 108
  __shared__ float w1s[DIM*17];
  __shared__ __align__(16) float h1s[FTR][DIM];      // 16 KB
  __shared__ float part[FTR][DIM][2];                // 32 KB
  for (int i = t; i < (FTR+4)*CIN; i += 256) {
    int row = c0 + i/3, ch = i - (i/3)*3;
    xs[i] = (row < TSEQ) ? x[(size_t)b*TSEQ*CIN + (size_t)row*CIN + ch] : 0.f;
  }
  for (int i = t; i < DIM*15; i += 256) {
    int j = i/15, k = i - j*15;
    w1s[j*17+k] = w1[i];
  }
  __syncthreads();
  {
    int j = t & 127, rh = t >> 7;
    float bias = b1[j];
    const float* wr = &w1s[j*17];
    for (int r = rh*16; r < rh*16+16; ++r) {
      float a = bias;
#pragma unroll
      for (int k = 0; k < 15; ++k) a += xs[r*3+k]*wr[k];
      h1s[r][j] = 0.5f*a*(1.f + erff(a*0.70710678118654752f));  // exact gelu
    }
  }
  __syncthreads();
  {
    int j = t & 127, hf = t >> 7;
    float4 wv[16];
    const float4* w2r = (const float4*)(w2 + (size_t)j*DIM + hf*64);
#pragma unroll
    for (int k4 = 0; k4 < 16; ++k4) wv[k4] = w2r[k4];
#pragma unroll 2
    for (int r = 0; r < FTR; ++r) {
      const float4* hr = (const float4*)&h1s[r][hf*64];
      float acc = 0.f;
#pragma unroll
      for (int k4 = 0; k4 < 16; ++k4) {
        float4 hv = hr[k4];
        acc += wv[k4].x*hv.x + wv[k4].y*hv.y + wv[k4].z*hv.z + wv[k4].w*hv.w;
      }
      part[r][j][hf] = acc;
    }
  }
  __syncthreads();
  if (t < DIM) {
    float bias = b2[t];
    for (int r = 0; r < FTR; ++r) {
      int l = c0 + r;
      if (l < LSEQ) h[((size_t)b*LH + l)*DIM + t] = part[r][t][0] + part[r][t][1] + bias;
    }
  }
}

// ---------------------------------------------------------------- in_proj (+ dt softplus)
// grid: BATCH*128, block 256. J=6 (3 float2 pairs); double-buffered weight prefetch.
// NOTE (R5): epilogue compile-time unrolled (dynamic index -> scratch spill).
// NOTE (R6): weights read k-major from wT (coalesced).
#define TR2 16
__global__ void __launch_bounds__(256) k_inproj(
    const float* __restrict__ h, const float* __restrict__ wT,
    const float* __restrict__ dtb, float* __restrict__ zx) {
  const int nblk_l = 128;
  int b = blockIdx.x / nblk_l;
  int l0 = (blockIdx.x % nblk_l) * TR2;
  int t = threadIdx.x;
  __shared__ __align__(16) float hs[TR2][DIM];
  for (int i = t; i < TR2*DIM; i += 256) {
    int r = i >> 7, k = i & 127;
    int l = l0 + r;
    hs[r][k] = (l < LH) ? h[((size_t)b*LH + l)*DIM + k] : 0.f;
  }
  __syncthreads();
  int t7 = t & 127, half = t >> 7;
  int rbase = half * 8;
  bool j2ok = (t7 < 66);                    // pair j = 2t7+512,+513 valid (<= 643)
  int j2off = j2ok ? 2*t7 + 512 : 2*t7;
  float2 acc[3][8];
#pragma unroll
  for (int p = 0; p < 3; ++p)
#pragma unroll
    for (int r = 0; r < 8; ++r) acc[p][r] = make_float2(0.f, 0.f);
  float2 wcur[3][4], wnxt[3][4];
#pragma unroll
  for (int c = 0; c < 4; ++c) {             // prefetch k4 = 0
    const float* wrow = wT + (size_t)c*DPROJ;
    wcur[0][c] = *(const float2*)(wrow + 2*t7);
    wcur[1][c] = *(const float2*)(wrow + 2*t7 + 256);
    wcur[2][c] = *(const float2*)(wrow + j2off);
  }
#pragma unroll 2
  for (int k4 = 0; k4 < 32; ++k4) {
    if (k4 + 1 < 32) {                      // prefetch next k-slice (hides latency)
#pragma unroll
      for (int c = 0; c < 4; ++c) {
        const float* wrow = wT + (size_t)((k4+1)*4 + c)*DPROJ;
        wnxt[0][c] = *(const float2*)(wrow + 2*t7);
        wnxt[1][c] = *(const float2*)(wrow + 2*t7 + 256);
        wnxt[2][c] = *(const float2*)(wrow + j2off);
      }
    }
#pragma unroll
    for (int r = 0; r < 8; ++r) {
      float4 hv = *(const float4*)(&hs[rbase + r][k4*4]);  // wave-broadcast
      acc[0][r].x += wcur[0][0].x*hv.x + wcur[0][1].x*hv.y + wcur[0][2].x*hv.z + wcur[0][3].x*hv.w;
      acc[0][r].y += wcur[0][0].y*hv.x + wcur[0][1].y*hv.y + wcur[0][2].y*hv.z + wcur[0][3].y*hv.w;
      acc[1][r].x += wcur[1][0].x*hv.x + wcur[1][1].x*hv.y + wcur[1][2].x*hv.z + wcur[1][3].x*hv.w;
      acc[1][r].y += wcur[1][0].y*hv.x + wcur[1][1].y*hv.y + wcur[1][2].y*hv.z + wcur[1][3].y*hv.w;
      acc[2][r].x += wcur[2][0].x*hv.x + wcur[2][1].x*hv.y + wcur[2][2].x*hv.z + wcur[2][3].x*hv.w;
      acc[2][r].y += wcur[2][0].y*hv.x + wcur[2][1].y*hv.y + wcur[2][2].y*hv.z + wcur[2][3].y*hv.w;
    }
#pragma unroll
    for (int p = 0; p < 3; ++p)
#pragma unroll
      for (int c = 0; c < 4; ++c) wcur[p][c] = wnxt[p][c];
  }
  bool isdt = j2ok && (t7 >= 64);           // j = 2t7+512 >= 640 -> t7 in {64,65}
  float bias0 = 0.f, bias1 = 0.f;
  if (isdt) { bias0 = dtb[2*t7 - 128]; bias1 = dtb[2*t7 - 127]; }
#pragma unroll
  for (int r = 0; r < 8; ++r) {             // compile-time: acc stays in VGPRs
    int l = l0 + rbase + r;
    if (l >= LH) continue;
    size_t row = ((size_t)b*LH + l)*DPROJ;
    *(float2*)(zx + row + 2*t7)       = acc[0][r];
    *(float2*)(zx + row + 2*t7 + 256) = acc[1][r];
    if (j2ok) {
      float2 v = acc[2][r];
      if (isdt) {
        v.x += bias0; v.x = (v.x > 20.f) ? v.x : log1pf(__expf(v.x));
        v.y += bias1; v.y = (v.y > 20.f) ? v.y : log1pf(__expf(v.y));
      }
      *(float2*)(zx + row + 2*t7 + 512) = v;
    }
  }
}

// ---------------------------------------------------------------- chunked SSD, phase A
// Conv+silu fused into staging (xbc buffer eliminated). grid 1024, block 256.
__global__ void __launch_bounds__(256) k_chunk_state(
    const float* __restrict__ zx, const float* __restrict__ cw,
    const float* __restrict__ cb, const float* __restrict__ A_log,
    float* __restrict__ G, float* __restrict__ dec) {
  int blk = blockIdx.x;
  int c = blk & (NCH-1), hd = (blk >> 5) & 3, b = blk >> 7;
  int t0 = c*QC;
  int tid = threadIdx.x;
  float A = -__expf(A_log[hd]);
  __shared__ float xs[QC*PDIM];     // [s][p]
  __shared__ float Bs[QC*NSTATE];   // [s][n]
  __shared__ float coef[QC];
  if (tid < 64) {
    int tg = t0 + tid;
    float dtv = (tg < LH) ? zx[((size_t)b*LH + tg)*DPROJ + 640 + hd] : 0.f;
    float s = dtv;
#pragma unroll
    for (int off = 1; off < 64; off <<= 1) {
      float u = __shfl_up(s, off);
      if (tid >= off) s += u;
    }
    float cq = __shfl(s, 63);
    coef[tid] = __expf(A*(cq - s)) * dtv;
    if (tid == 63) dec[blk] = __expf(A * s);
  }
  for (int i = tid; i < QC*64; i += 256) {
    int s = i >> 6, j = i & 63;
    int tg = t0 + s;
    float xv = 0.f, bv = 0.f;
    if (tg < LH) {
      xv = convch(zx, cw, cb, b, tg, hd*PDIM + j);   // x-slice channel
      bv = convch(zx, cw, cb, b, tg, DIN + j);       // B channel 256+j
    }
    xs[i] = xv; Bs[i] = bv;
  }
  __syncthreads();
  int n = tid >> 2, q = tid & 3;
  float4 acc[4];
#pragma unroll
  for (int i4 = 0; i4 < 4; ++i4) acc[i4] = make_float4(0.f,0.f,0.f,0.f);
  const float4* xs4 = (const float4*)xs;
#pragma unroll 4
  for (int s = 0; s < QC; ++s) {            // capped unroll: keep VGPRs < spill
    float cb_ = coef[s] * Bs[s*64 + n];
#pragma unroll
    for (int i4 = 0; i4 < 4; ++i4) {
      float4 xv = xs4[s*16 + q*4 + i4];
      acc[i4].x += cb_*xv.x; acc[i4].y += cb_*xv.y;
      acc[i4].z += cb_*xv.z; acc[i4].w += cb_*xv.w;
    }
  }
  float4* gp = (float4*)(G + (size_t)blk*4096 + n*64 + q*16);
#pragma unroll
  for (int i4 = 0; i4 < 4; ++i4) gp[i4] = acc[i4];
}

// ---------------------------------------------------------------- phase B: inter-chunk
__global__ void __launch_bounds__(256) k_combine(
    const float* __restrict__ G, const float* __restrict__ dec, float* __restrict__ Hin) {
  int bh = blockIdx.x >> 2, esp = blockIdx.x & 3;
  int e = esp*1024 + threadIdx.x*4;
  size_t base0 = (size_t)bh*NCH*4096 + e;
  float4 H = make_float4(0.f,0.f,0.f,0.f);
  float4 g = *(const float4*)(G + base0);
  float d = dec[bh*NCH];
  for (int c = 0; c < NCH; ++c) {
    float4 gn = make_float4(0.f,0.f,0.f,0.f); float dn = 0.f;
    if (c + 1 < NCH) {
      gn = *(const float4*)(G + base0 + (size_t)(c+1)*4096);
      dn = dec[bh*NCH + c + 1];
    }
    *(float4*)(Hin + base0 + (size_t)c*4096) = H;   // carry-in for chunk c
    H.x = H.x*d + g.x; H.y = H.y*d + g.y; H.z = H.z*d + g.z; H.w = H.w*d + g.w;
    g = gn; d = dn;
  }
}

// ---------------------------------------------------------------- phase C: chunk output
// Conv+silu fused into B/C/X staging. grid 1024, block 256.
__global__ void __launch_bounds__(256) k_chunk_out(
    const float* __restrict__ zx, const float* __restrict__ cw,
    const float* __restrict__ cb, const float* __restrict__ A_log,
    const float* __restrict__ Hin, float* __restrict__ y) {
  int blk = blockIdx.x;
  int c = blk & (NCH-1), hd = (blk >> 5) & 3, b = blk >> 7;
  int t0 = c*QC;
  int tid = threadIdx.x;
  int tr = tid >> 4, tc = tid & 15;
  float A = -__expf(A_log[hd]);
  __shared__ __align__(16) float SA[QC*LDP];   // B, then X
  __shared__ __align__(16) float SB[QC*LDP];   // C
  __shared__ __align__(16) float SC[QC*LDP];   // M, then HT
  __shared__ float cum[QC], dts[QC], pref[QC];
  if (tid < 64) {
    int tg = t0 + tid;
    float dtv = (tg < LH) ? zx[((size_t)b*LH + tg)*DPROJ + 640 + hd] : 0.f;
    float s = dtv;
#pragma unroll
    for (int off = 1; off < 64; off <<= 1) {
      float u = __shfl_up(s, off);
      if (tid >= off) s += u;
    }
    dts[tid] = dtv; cum[tid] = s; pref[tid] = __expf(A*s);
  }
  for (int i = tid; i < QC*64; i += 256) {
    int s = i >> 6, j = i & 63;
    int tg = t0 + s;
    float bv = 0.f, cv = 0.f;
    if (tg < LH) {
      bv = convch(zx, cw, cb, b, tg, DIN + j);            // B channel 256+j
      cv = convch(zx, cw, cb, b, tg, DIN + NSTATE + j);   // C channel 320+j
    }
    SA[s*LDP + j] = bv; SB[s*LDP + j] = cv;
  }
  __syncthreads();
  // ---- S = C B^T
  float S[4][4];
#pragma unroll
  for (int j = 0; j < 4; ++j)
#pragma unroll
    for (int i = 0; i < 4; ++i) S[j][i] = 0.f;
  const float4* SA4 = (const float4*)SA;
  const float4* SB4 = (const float4*)SB;
#pragma unroll 2
  for (int n4 = 0; n4 < 16; ++n4) {
    float4 cv[4], bv[4];
#pragma unroll
    for (int j = 0; j < 4; ++j) cv[j] = SB4[(tr + 16*j)*(LDP/4) + n4];
#pragma unroll
    for (int i = 0; i < 4; ++i) bv[i] = SA4[(tc + 16*i)*(LDP/4) + n4];
#pragma unroll
    for (int j = 0; j < 4; ++j)
#pragma unroll
      for (int i = 0; i < 4; ++i)
        S[j][i] += cv[j].x*bv[i].x + cv[j].y*bv[i].y + cv[j].z*bv[i].z + cv[j].w*bv[i].w;
  }
  __syncthreads();
  // ---- masked decay -> M in SC; reload X (fused conv) into SA
#pragma unroll
  for (int j = 0; j < 4; ++j) {
    int t = tr + 16*j;
#pragma unroll
    for (int i = 0; i < 4; ++i) {
      int s = tc + 16*i;
      float m = 0.f;
      if (s <= t) m = S[j][i] * __expf(A*(cum[t] - cum[s])) * dts[s];
      SC[t*LDP + s] = m;
    }
  }
  for (int i = tid; i < QC*64; i += 256) {
    int s = i >> 6, j = i & 63;
    int tg = t0 + s;
    SA[s*LDP + j] = (tg < LH) ? convch(zx, cw, cb, b, tg, hd*PDIM + j) : 0.f;
  }
  __syncthreads();
  // ---- Y1 = M X
  float4 y1[4];
#pragma unroll
  for (int j = 0; j < 4; ++j) y1[j] = make_float4(0.f,0.f,0.f,0.f);
  const float4* SC4 = (const float4*)SC;
#pragma unroll 2
  for (int s4 = 0; s4 < 16; ++s4) {
    float4 mj[4], xk[4];
#pragma unroll
    for (int j = 0; j < 4; ++j) mj[j] = SC4[(tr + 16*j)*(LDP/4) + s4];
#pragma unroll
    for (int k = 0; k < 4; ++k) xk[k] = SA4[(s4*4 + k)*(LDP/4) + tc];
#pragma unroll
    for (int j = 0; j < 4; ++j) {
      y1[j].x += mj[j].x*xk[0].x + mj[j].y*xk[1].x + mj[j].z*xk[2].x + mj[j].w*xk[3].x;
      y1[j].y += mj[j].x*xk[0].y + mj[j].y*xk[1].y + mj[j].z*xk[2].y + mj[j].w*xk[3].y;
      y1[j].z += mj[j].x*xk[0].z + mj[j].y*xk[1].z + mj[j].z*xk[2].z + mj[j].w*xk[3].z;
      y1[j].w += mj[j].x*xk[0].w + mj[j].y*xk[1].w + mj[j].z*xk[2].w + mj[j].w*xk[3].w;
    }
  }
  __syncthreads();
  // ---- load HT (flat [n*64+p]) into SC
  size_t hbase = (size_t)blk*4096;
  for (int i = tid; i < 4096; i += 256) SC[(i >> 6)*LDP + (i & 63)] = Hin[hbase + i];
  __syncthreads();
  // ---- Y2 = C H_in^T
  float4 y2[4];
#pragma unroll
  for (int j = 0; j < 4; ++j) y2[j] = make_float4(0.f,0.f,0.f,0.f);
#pragma unroll 2
  for (int n4 = 0; n4 < 16; ++n4) {
    float4 cj[4], hk[4];
#pragma unroll
    for (int j = 0; j < 4; ++j) cj[j] = SB4[(tr + 16*j)*(LDP/4) + n4];
#pragma unroll
    for (int k = 0; k < 4; ++k) hk[k] = SC4[(n4*4 + k)*(LDP/4) + tc];
#pragma unroll
    for (int j = 0; j < 4; ++j) {
      y2[j].x += cj[j].x*hk[0].x + cj[j].y*hk[1].x + cj[j].z*hk[2].x + cj[j].w*hk[3].x;
      y2[j].y += cj[j].x*hk[0].y + cj[j].y*hk[1].y + cj[j].z*hk[2].y + cj[j].w*hk[3].y;
      y2[j].z += cj[j].x*hk[0].z + cj[j].y*hk[1].z + cj[j].z*hk[2].z + cj[j].w*hk[3].z;
      y2[j].w += cj[j].x*hk[0].w + cj[j].y*hk[1].w + cj[j].z*hk[2].w + cj[j].w*hk[3].w;
    }
  }
#pragma unroll
  for (int j = 0; j < 4; ++j) {
    int t = tr + 16*j, tg = t0 + t;
    if (tg < LH) {
      float pr = pref[t];
      float4 o;
      o.x = y1[j].x + pr*y2[j].x;
      o.y = y1[j].y + pr*y2[j].y;
      o.z = y1[j].z + pr*y2[j].z;
      o.w = y1[j].w + pr*y2[j].w;
      *(float4*)(y + ((size_t)b*LH + tg)*DIN + hd*PDIM + tc*4) = o;
    }
  }
}

// ---------------------------------------------------------------- gate + rmsnorm + out_proj
// R7 structure (known-good) + fused conv for the gate x-term. grid BATCH*256, block 256.
#define TR5 8
__global__ void __launch_bounds__(256) k_out(
    const float* __restrict__ y, const float* __restrict__ zx,
    const float* __restrict__ cw, const float* __restrict__ cb,
    const float* __restrict__ Dh, const float* __restrict__ nw,
    const float* __restrict__ owT, float* __restrict__ h) {
  const int nblk_l = 256;
  int b = blockIdx.x / nblk_l;
  int l0 = (blockIdx.x % nblk_l) * TR5;
  int t = threadIdx.x;
  __shared__ __align__(16) float yv[TR5][DIN];
  __shared__ float part[4][TR5][DIM];          // 16 KB quarter partials
  __shared__ float red[TR5][4];
  __shared__ float rs[TR5];
  int c = t;
  int hd = c >> 6;
  float dcoef = Dh[hd];
  float nwc = nw[c];
  float v[TR5];
#pragma unroll
  for (int r = 0; r < TR5; ++r) {
    int l = l0 + r;
    float val = 0.f;
    if (l < LH) {
      size_t row = (size_t)b*LH + l;
      float ys = y[row*DIN + c];
      float xh = convch(zx, cw, cb, b, l, c);    // gate x-term channel c
      float z  = zx[row*DPROJ + c];
      val = (ys + dcoef*xh) * siluf_(z);
    }
    v[r] = val;
  }
  int wave = t >> 6, lane = t & 63;
#pragma unroll
  for (int r = 0; r < TR5; ++r) {
    float sq = v[r]*v[r];
    for (int off = 32; off > 0; off >>= 1) sq += __shfl_down(sq, off);
    if (lane == 0) red[r][wave] = sq;
  }
  __syncthreads();
  if (t < TR5) {
    float sm = red[t][0]+red[t][1]+red[t][2]+red[t][3];
    rs[t] = rsqrtf(sm/(float)DIN + 1e-5f);
  }
  __syncthreads();
#pragma unroll
  for (int r = 0; r < TR5; ++r) yv[r][c] = v[r] * rs[r] * nwc;
  __syncthreads();
  int jp = t & 63, q = t >> 6;
  int j0 = jp*2;
  float acc[2][TR5];
#pragma unroll
  for (int jj = 0; jj < 2; ++jj)
#pragma unroll
    for (int r = 0; r < TR5; ++r) acc[jj][r] = 0.f;
  const float* wtb = owT + (size_t)q*64*DIM + j0;
#pragma unroll 2
  for (int k4 = 0; k4 < 16; ++k4) {
    float2 w0 = *(const float2*)(wtb + (k4*4+0)*DIM);   // coalesced (8B/lane)
    float2 w1 = *(const float2*)(wtb + (k4*4+1)*DIM);
    float2 w2_ = *(const float2*)(wtb + (k4*4+2)*DIM);
    float2 w3 = *(const float2*)(wtb + (k4*4+3)*DIM);
#pragma unroll
    for (int r = 0; r < TR5; ++r) {
      float4 hv = ((const float4*)&yv[r][q*64])[k4];  // broadcast
      acc[0][r] += w0.x*hv.x + w1.x*hv.y + w2_.x*hv.z + w3.x*hv.w;
      acc[1][r] += w0.y*hv.x + w1.y*hv.y + w2_.y*hv.z + w3.y*hv.w;
    }
  }
#pragma unroll
  for (int r = 0; r < TR5; ++r) {
    part[q][r][j0]   = acc[0][r];
    part[q][r][j0+1] = acc[1][r];
  }
  __syncthreads();
  if (t < DIM) {
#pragma unroll 2
    for (int r = 0; r < TR5; ++r) {
      int l = l0 + r;
      if (l < LH)
        h[((size_t)b*LH + l)*DIM + t] =
            part[0][r][t] + part[1][r][t] + part[2][r][t] + part[3][r][t];
    }
  }
}

// ---------------------------------------------------------------- final LN + head
__global__ void k_head(const float* __restrict__ h, const float* __restrict__ lnw,
                       const float* __restrict__ lnb, const float* __restrict__ hw,
                       const float* __restrict__ hb, float* __restrict__ out) {
  int b = blockIdx.x; int t = threadIdx.x;
  __shared__ float red[2];
  int wave = t >> 6, lane = t & 63;
  float v = h[((size_t)b*LH + LSEQ)*DIM + t];
  float s = v;
  for (int off = 32; off > 0; off >>= 1) s += __shfl_down(s, off);
  if (lane == 0) red[wave] = s;
  __syncthreads();
  float mean = (red[0]+red[1]) / (float)DIM;
  __syncthreads();
  float d = v - mean; float sq = d*d;
  for (int off = 32; off > 0; off >>= 1) sq += __shfl_down(sq, off);
  if (lane == 0) red[wave] = sq;
  __syncthreads();
  float var = (red[0]+red[1]) / (float)DIM;
  float cn = d*rsqrtf(var + 1e-5f)*lnw[t] + lnb[t];
  float dot = cn*hw[t];
  __syncthreads();
  for (int off = 32; off > 0; off >>= 1) dot += __shfl_down(dot, off);
  if (lane == 0) red[wave] = dot;
  __syncthreads();
  if (t == 0) out[b] = red[0]+red[1] + hb[0];
}

// ---------------------------------------------------------------- h -> d_out copy
__global__ void k_copy(const float* __restrict__ src, float* __restrict__ dst, long n4) {
  long i = (long)blockIdx.x*blockDim.x + threadIdx.x;
  if (i < n4) ((float4*)dst)[i] = ((const float4*)src)[i];
}

extern "C" void kernel_launch(void* const* d_in, const int* in_sizes, int n_in,
                              void* d_out, int out_size, void* d_ws, size_t ws_size,
                              hipStream_t stream) {
  const float* x     = (const float*)d_in[0];
  const float* w1    = (const float*)d_in[1];
  const float* b1    = (const float*)d_in[2];
  const float* w2    = (const float*)d_in[3];
  const float* b2    = (const float*)d_in[4];
  const float* cls   = (const float*)d_in[5];
  const float* inw   = (const float*)d_in[6];   // (4, 644, 128)
  const float* cw    = (const float*)d_in[7];   // (4, 384, 4)
  const float* cb    = (const float*)d_in[8];   // (4, 384)
  const float* dtb   = (const float*)d_in[9];   // (4, 4)
  const float* Alog  = (const float*)d_in[10];  // (4, 4)
  const float* Dh    = (const float*)d_in[11];  // (4, 4)
  const float* nw    = (const float*)d_in[12];  // (4, 256)
  const float* ow    = (const float*)d_in[13];  // (4, 128, 256)
  const float* lnw   = (const float*)d_in[14];
  const float* lnb   = (const float*)d_in[15];
  const float* hw    = (const float*)d_in[16];
  const float* hb    = (const float*)d_in[17];

  float* ws   = (float*)d_ws;
  float* hbuf = ws;                                   // 2,094,080
  float* zx   = hbuf + (size_t)BATCH*LH*DIM;          // 10,535,840
  float* ybuf = zx   + (size_t)BATCH*LH*DPROJ;        // 4,194,304 (G aliases ybuf)
  float* G    = ybuf;                                 //   (consumed before y written)
  float* Hin  = ybuf + 4194304;                       // 4,194,304
  float* dec  = Hin  + 4194304;                       // 1,024
  float* inwT = dec  + 1024;                          // 4*128*644 = 329,728
  float* owT  = inwT + 329728;                        // 4*256*128 = 131,072
  // total: 21,480,352 floats = 85.9 MiB

  k_transpose<<<dim3(2,11,4), 256, 0, stream>>>(inw, inwT, DPROJ, DIM);
  k_transpose<<<dim3(4,2,4),  256, 0, stream>>>(ow,  owT,  DIM, DIN);

  k_front<<<BATCH*64 + 1, 256, 0, stream>>>(x, w1, b1, w2, b2, cls, hbuf);

  for (int i = 0; i < DEPTH; ++i) {
    const float* cwl = cw + (size_t)i*CONVD*4;
    const float* cbl = cb + (size_t)i*CONVD;
    k_inproj<<<BATCH*128, 256, 0, stream>>>(
        hbuf, inwT + (size_t)i*DPROJ*DIM, dtb + i*NH, zx);
    k_chunk_state<<<BATCH*NH*NCH, 256, 0, stream>>>(zx, cwl, cbl, Alog + i*NH, G, dec);
    k_combine<<<BATCH*NH*4, 256, 0, stream>>>(G, dec, Hin);
    k_chunk_out<<<BATCH*NH*NCH, 256, 0, stream>>>(zx, cwl, cbl, Alog + i*NH, Hin, ybuf);
    k_out<<<BATCH*256, 256, 0, stream>>>(
        ybuf, zx, cwl, cbl, Dh + i*NH, nw + (size_t)i*DIN,
        owT + (size_t)i*DIM*DIN, hbuf);
  }

  k_head<<<BATCH, 128, 0, stream>>>(hbuf, lnw, lnb, hw, hb, (float*)d_out);
  {
    long n4 = (long)BATCH*LH*DIM/4;
    k_copy<<<(int)((n4 + 255)/256), 256, 0, stream>>>(hbuf, (float*)d_out + 8, n4);
  }
}

// Round 10
// 948.251 us; speedup vs baseline: 1.3555x; 1.3555x over previous
//
#include <hip/hip_runtime.h>
#include <math.h>

// Shapes (fixed by setup_inputs)
#define BATCH 8
#define TSEQ 2048
#define CIN 3
#define WIN 5
#define LSEQ 2044          // T - WIN + 1
#define LH 2045            // LSEQ + 1 (cls token appended)
#define DIM 128
#define DEPTH 4
#define DIN 256            // d_inner
#define NH 4               // heads
#define PDIM 64            // headdim
#define NSTATE 64          // d_state
#define CONVD 384          // d_inner + 2*d_state
#define DPROJ 644          // 2*d_inner + 2*d_state + nheads
#define QC 64              // chunk length
#define NCH 32             // number of chunks (32*64 = 2048 >= 2045)
#define LDP 68             // padded LDS row stride (17 float4s; bank-spread)
#define FTR 32             // tokens per k_front block

__device__ __forceinline__ float sigmoidf_(float x){ return 1.f/(1.f+__expf(-x)); }
__device__ __forceinline__ float siluf_(float x){ return x*sigmoidf_(x); }

// ---------------------------------------------------------------- weight transpose
__global__ void __launch_bounds__(256) k_transpose(
    const float* __restrict__ src, float* __restrict__ dst, int R, int C) {
  __shared__ float tile[64][65];
  const float* s = src + (size_t)blockIdx.z*R*C;
  float* d = dst + (size_t)blockIdx.z*R*C;
  int r0 = blockIdx.y*64, c0 = blockIdx.x*64;
  int tx = threadIdx.x & 63, ty = threadIdx.x >> 6;
  for (int rr = ty; rr < 64; rr += 4) {
    int r = r0 + rr, c = c0 + tx;
    if (r < R && c < C) tile[rr][tx] = s[(size_t)r*C + c];
  }
  __syncthreads();
  for (int cc = ty; cc < 64; cc += 4) {
    int c = c0 + cc, r = r0 + tx;
    if (c < C && r < R) d[(size_t)c*R + r] = tile[tx][cc];
  }
}

// ---------------------------------------------------------------- front MLP
__global__ void __launch_bounds__(256) k_front(
    const float* __restrict__ x, const float* __restrict__ w1,
    const float* __restrict__ b1, const float* __restrict__ w2,
    const float* __restrict__ b2, const float* __restrict__ cls,
    float* __restrict__ h) {
  int t = threadIdx.x;
  if (blockIdx.x == BATCH*64) {              // cls rows
    if (t < DIM) {
      float cv = cls[t];
      for (int b = 0; b < BATCH; ++b) h[((size_t)b*LH + LSEQ)*DIM + t] = cv;
    }
    return;
  }
  int b = blockIdx.x >> 6;
  int c0 = (blockIdx.x & 63) * FTR;
  __shared__ float xs[(FTR+4)*CIN];                  // 108
  __shared__ float w1s[DIM*17];
  __shared__ __align__(16) float h1s[FTR][DIM];      // 16 KB
  __shared__ float part[FTR][DIM][2];                // 32 KB
  for (int i = t; i < (FTR+4)*CIN; i += 256) {
    int row = c0 + i/3, ch = i - (i/3)*3;
    xs[i] = (row < TSEQ) ? x[(size_t)b*TSEQ*CIN + (size_t)row*CIN + ch] : 0.f;
  }
  for (int i = t; i < DIM*15; i += 256) {
    int j = i/15, k = i - j*15;
    w1s[j*17+k] = w1[i];
  }
  __syncthreads();
  {
    int j = t & 127, rh = t >> 7;
    float bias = b1[j];
    const float* wr = &w1s[j*17];
    for (int r = rh*16; r < rh*16+16; ++r) {
      float a = bias;
#pragma unroll
      for (int k = 0; k < 15; ++k) a += xs[r*3+k]*wr[k];
      h1s[r][j] = 0.5f*a*(1.f + erff(a*0.70710678118654752f));  // exact gelu
    }
  }
  __syncthreads();
  {
    int j = t & 127, hf = t >> 7;
    float4 wv[16];
    const float4* w2r = (const float4*)(w2 + (size_t)j*DIM + hf*64);
#pragma unroll
    for (int k4 = 0; k4 < 16; ++k4) wv[k4] = w2r[k4];
#pragma unroll 2
    for (int r = 0; r < FTR; ++r) {
      const float4* hr = (const float4*)&h1s[r][hf*64];
      float acc = 0.f;
#pragma unroll
      for (int k4 = 0; k4 < 16; ++k4) {
        float4 hv = hr[k4];
        acc += wv[k4].x*hv.x + wv[k4].y*hv.y + wv[k4].z*hv.z + wv[k4].w*hv.w;
      }
      part[r][j][hf] = acc;
    }
  }
  __syncthreads();
  if (t < DIM) {
    float bias = b2[t];
    for (int r = 0; r < FTR; ++r) {
      int l = c0 + r;
      if (l < LSEQ) h[((size_t)b*LH + l)*DIM + t] = part[r][t][0] + part[r][t][1] + bias;
    }
  }
}

// ---------------------------------------------------------------- in_proj (+ dt softplus)
// grid: BATCH*128, block 256. J=6 (3 float2 pairs); double-buffered weight prefetch.
// NOTE (R5): epilogue compile-time unrolled (dynamic index -> scratch spill).
// NOTE (R6): weights read k-major from wT (coalesced).
#define TR2 16
__global__ void __launch_bounds__(256) k_inproj(
    const float* __restrict__ h, const float* __restrict__ wT,
    const float* __restrict__ dtb, float* __restrict__ zx) {
  const int nblk_l = 128;
  int b = blockIdx.x / nblk_l;
  int l0 = (blockIdx.x % nblk_l) * TR2;
  int t = threadIdx.x;
  __shared__ __align__(16) float hs[TR2][DIM];
  for (int i = t; i < TR2*DIM; i += 256) {
    int r = i >> 7, k = i & 127;
    int l = l0 + r;
    hs[r][k] = (l < LH) ? h[((size_t)b*LH + l)*DIM + k] : 0.f;
  }
  __syncthreads();
  int t7 = t & 127, half = t >> 7;
  int rbase = half * 8;
  bool j2ok = (t7 < 66);                    // pair j = 2t7+512,+513 valid (<= 643)
  int j2off = j2ok ? 2*t7 + 512 : 2*t7;
  float2 acc[3][8];
#pragma unroll
  for (int p = 0; p < 3; ++p)
#pragma unroll
    for (int r = 0; r < 8; ++r) acc[p][r] = make_float2(0.f, 0.f);
  float2 wcur[3][4], wnxt[3][4];
#pragma unroll
  for (int c = 0; c < 4; ++c) {             // prefetch k4 = 0
    const float* wrow = wT + (size_t)c*DPROJ;
    wcur[0][c] = *(const float2*)(wrow + 2*t7);
    wcur[1][c] = *(const float2*)(wrow + 2*t7 + 256);
    wcur[2][c] = *(const float2*)(wrow + j2off);
  }
#pragma unroll 2
  for (int k4 = 0; k4 < 32; ++k4) {
    if (k4 + 1 < 32) {                      // prefetch next k-slice (hides latency)
#pragma unroll
      for (int c = 0; c < 4; ++c) {
        const float* wrow = wT + (size_t)((k4+1)*4 + c)*DPROJ;
        wnxt[0][c] = *(const float2*)(wrow + 2*t7);
        wnxt[1][c] = *(const float2*)(wrow + 2*t7 + 256);
        wnxt[2][c] = *(const float2*)(wrow + j2off);
      }
    }
#pragma unroll
    for (int r = 0; r < 8; ++r) {
      float4 hv = *(const float4*)(&hs[rbase + r][k4*4]);  // wave-broadcast
      acc[0][r].x += wcur[0][0].x*hv.x + wcur[0][1].x*hv.y + wcur[0][2].x*hv.z + wcur[0][3].x*hv.w;
      acc[0][r].y += wcur[0][0].y*hv.x + wcur[0][1].y*hv.y + wcur[0][2].y*hv.z + wcur[0][3].y*hv.w;
      acc[1][r].x += wcur[1][0].x*hv.x + wcur[1][1].x*hv.y + wcur[1][2].x*hv.z + wcur[1][3].x*hv.w;
      acc[1][r].y += wcur[1][0].y*hv.x + wcur[1][1].y*hv.y + wcur[1][2].y*hv.z + wcur[1][3].y*hv.w;
      acc[2][r].x += wcur[2][0].x*hv.x + wcur[2][1].x*hv.y + wcur[2][2].x*hv.z + wcur[2][3].x*hv.w;
      acc[2][r].y += wcur[2][0].y*hv.x + wcur[2][1].y*hv.y + wcur[2][2].y*hv.z + wcur[2][3].y*hv.w;
    }
#pragma unroll
    for (int p = 0; p < 3; ++p)
#pragma unroll
      for (int c = 0; c < 4; ++c) wcur[p][c] = wnxt[p][c];
  }
  bool isdt = j2ok && (t7 >= 64);           // j = 2t7+512 >= 640 -> t7 in {64,65}
  float bias0 = 0.f, bias1 = 0.f;
  if (isdt) { bias0 = dtb[2*t7 - 128]; bias1 = dtb[2*t7 - 127]; }
#pragma unroll
  for (int r = 0; r < 8; ++r) {             // compile-time: acc stays in VGPRs
    int l = l0 + rbase + r;
    if (l >= LH) continue;
    size_t row = ((size_t)b*LH + l)*DPROJ;
    *(float2*)(zx + row + 2*t7)       = acc[0][r];
    *(float2*)(zx + row + 2*t7 + 256) = acc[1][r];
    if (j2ok) {
      float2 v = acc[2][r];
      if (isdt) {
        v.x += bias0; v.x = (v.x > 20.f) ? v.x : log1pf(__expf(v.x));
        v.y += bias1; v.y = (v.y > 20.f) ? v.y : log1pf(__expf(v.y));
      }
      *(float2*)(zx + row + 2*t7 + 512) = v;
    }
  }
}

// ---------------------------------------------------------------- causal dwconv + silu
// (R9 lesson: materialize once — fusing this into consumers recomputes conv+exp
// 2-3x with scattered loads and doubled k_chunk_out. Keep separate.)
__global__ void k_conv(const float* __restrict__ zx, const float* __restrict__ cw,
                       const float* __restrict__ cb, float* __restrict__ xbc) {
  size_t idx = (size_t)blockIdx.x*blockDim.x + threadIdx.x;
  const size_t total = (size_t)BATCH*LH*CONVD;
  if (idx >= total) return;
  int c = (int)(idx % CONVD);
  size_t bl = idx / CONVD;
  int l = (int)(bl % LH); int b = (int)(bl / LH);
  float acc = cb[c];
#pragma unroll
  for (int k = 0; k < 4; ++k) {
    int tin = l - 3 + k;
    if (tin >= 0) acc += zx[((size_t)b*LH + tin)*DPROJ + DIN + c] * cw[c*4 + k];
  }
  xbc[idx] = siluf_(acc);
}

// ---------------------------------------------------------------- chunked SSD, phase A
__global__ void __launch_bounds__(256) k_chunk_state(
    const float* __restrict__ zx, const float* __restrict__ xbc,
    const float* __restrict__ A_log, float* __restrict__ G, float* __restrict__ dec) {
  int blk = blockIdx.x;
  int c = blk & (NCH-1), hd = (blk >> 5) & 3, b = blk >> 7;
  int t0 = c*QC;
  int tid = threadIdx.x;
  float A = -__expf(A_log[hd]);
  __shared__ float xs[QC*PDIM];     // [s][p]
  __shared__ float Bs[QC*NSTATE];   // [s][n]
  __shared__ float coef[QC];
  if (tid < 64) {
    int tg = t0 + tid;
    float dtv = (tg < LH) ? zx[((size_t)b*LH + tg)*DPROJ + 640 + hd] : 0.f;
    float s = dtv;
#pragma unroll
    for (int off = 1; off < 64; off <<= 1) {
      float u = __shfl_up(s, off);
      if (tid >= off) s += u;
    }
    float cq = __shfl(s, 63);
    coef[tid] = __expf(A*(cq - s)) * dtv;
    if (tid == 63) dec[blk] = __expf(A * s);
  }
  for (int i = tid; i < QC*64; i += 256) {
    int s = i >> 6, j = i & 63;
    int tg = t0 + s;
    float xv = 0.f, bv = 0.f;
    if (tg < LH) {
      size_t row = ((size_t)b*LH + tg)*CONVD;
      xv = xbc[row + hd*PDIM + j];
      bv = xbc[row + DIN + j];
    }
    xs[i] = xv; Bs[i] = bv;
  }
  __syncthreads();
  int n = tid >> 2, q = tid & 3;
  float4 acc[4];
#pragma unroll
  for (int i4 = 0; i4 < 4; ++i4) acc[i4] = make_float4(0.f,0.f,0.f,0.f);
  const float4* xs4 = (const float4*)xs;
#pragma unroll 4
  for (int s = 0; s < QC; ++s) {            // capped unroll: keep VGPRs < spill
    float cb_ = coef[s] * Bs[s*64 + n];
#pragma unroll
    for (int i4 = 0; i4 < 4; ++i4) {
      float4 xv = xs4[s*16 + q*4 + i4];
      acc[i4].x += cb_*xv.x; acc[i4].y += cb_*xv.y;
      acc[i4].z += cb_*xv.z; acc[i4].w += cb_*xv.w;
    }
  }
  float4* gp = (float4*)(G + (size_t)blk*4096 + n*64 + q*16);
#pragma unroll
  for (int i4 = 0; i4 < 4; ++i4) gp[i4] = acc[i4];
}

// ---------------------------------------------------------------- phase B: inter-chunk
__global__ void __launch_bounds__(256) k_combine(
    const float* __restrict__ G, const float* __restrict__ dec, float* __restrict__ Hin) {
  int bh = blockIdx.x >> 2, esp = blockIdx.x & 3;
  int e = esp*1024 + threadIdx.x*4;
  size_t base0 = (size_t)bh*NCH*4096 + e;
  float4 H = make_float4(0.f,0.f,0.f,0.f);
  float4 g = *(const float4*)(G + base0);
  float d = dec[bh*NCH];
  for (int c = 0; c < NCH; ++c) {
    float4 gn = make_float4(0.f,0.f,0.f,0.f); float dn = 0.f;
    if (c + 1 < NCH) {
      gn = *(const float4*)(G + base0 + (size_t)(c+1)*4096);
      dn = dec[bh*NCH + c + 1];
    }
    *(float4*)(Hin + base0 + (size_t)c*4096) = H;   // carry-in for chunk c
    H.x = H.x*d + g.x; H.y = H.y*d + g.y; H.z = H.z*d + g.z; H.w = H.w*d + g.w;
    g = gn; d = dn;
  }
}

// ---------------------------------------------------------------- phase C: chunk output
__global__ void __launch_bounds__(256) k_chunk_out(
    const float* __restrict__ zx, const float* __restrict__ xbc,
    const float* __restrict__ A_log, const float* __restrict__ Hin,
    float* __restrict__ y) {
  int blk = blockIdx.x;
  int c = blk & (NCH-1), hd = (blk >> 5) & 3, b = blk >> 7;
  int t0 = c*QC;
  int tid = threadIdx.x;
  int tr = tid >> 4, tc = tid & 15;
  float A = -__expf(A_log[hd]);
  __shared__ __align__(16) float SA[QC*LDP];   // B, then X
  __shared__ __align__(16) float SB[QC*LDP];   // C
  __shared__ __align__(16) float SC[QC*LDP];   // M, then HT
  __shared__ float cum[QC], dts[QC], pref[QC];
  if (tid < 64) {
    int tg = t0 + tid;
    float dtv = (tg < LH) ? zx[((size_t)b*LH + tg)*DPROJ + 640 + hd] : 0.f;
    float s = dtv;
#pragma unroll
    for (int off = 1; off < 64; off <<= 1) {
      float u = __shfl_up(s, off);
      if (tid >= off) s += u;
    }
    dts[tid] = dtv; cum[tid] = s; pref[tid] = __expf(A*s);
  }
  for (int i = tid; i < QC*64; i += 256) {
    int s = i >> 6, j = i & 63;
    int tg = t0 + s;
    float bv = 0.f, cv = 0.f;
    if (tg < LH) {
      size_t row = ((size_t)b*LH + tg)*CONVD;
      bv = xbc[row + DIN + j];
      cv = xbc[row + DIN + NSTATE + j];
    }
    SA[s*LDP + j] = bv; SB[s*LDP + j] = cv;
  }
  __syncthreads();
  // ---- S = C B^T
  float S[4][4];
#pragma unroll
  for (int j = 0; j < 4; ++j)
#pragma unroll
    for (int i = 0; i < 4; ++i) S[j][i] = 0.f;
  const float4* SA4 = (const float4*)SA;
  const float4* SB4 = (const float4*)SB;
#pragma unroll 2
  for (int n4 = 0; n4 < 16; ++n4) {
    float4 cv[4], bv[4];
#pragma unroll
    for (int j = 0; j < 4; ++j) cv[j] = SB4[(tr + 16*j)*(LDP/4) + n4];
#pragma unroll
    for (int i = 0; i < 4; ++i) bv[i] = SA4[(tc + 16*i)*(LDP/4) + n4];
#pragma unroll
    for (int j = 0; j < 4; ++j)
#pragma unroll
      for (int i = 0; i < 4; ++i)
        S[j][i] += cv[j].x*bv[i].x + cv[j].y*bv[i].y + cv[j].z*bv[i].z + cv[j].w*bv[i].w;
  }
  __syncthreads();
  // ---- masked decay -> M in SC; reload X into SA
#pragma unroll
  for (int j = 0; j < 4; ++j) {
    int t = tr + 16*j;
#pragma unroll
    for (int i = 0; i < 4; ++i) {
      int s = tc + 16*i;
      float m = 0.f;
      if (s <= t) m = S[j][i] * __expf(A*(cum[t] - cum[s])) * dts[s];
      SC[t*LDP + s] = m;
    }
  }
  for (int i = tid; i < QC*64; i += 256) {
    int s = i >> 6, j = i & 63;
    int tg = t0 + s;
    SA[s*LDP + j] = (tg < LH) ? xbc[((size_t)b*LH + tg)*CONVD + hd*PDIM + j] : 0.f;
  }
  __syncthreads();
  // ---- Y1 = M X
  float4 y1[4];
#pragma unroll
  for (int j = 0; j < 4; ++j) y1[j] = make_float4(0.f,0.f,0.f,0.f);
  const float4* SC4 = (const float4*)SC;
#pragma unroll 2
  for (int s4 = 0; s4 < 16; ++s4) {
    float4 mj[4], xk[4];
#pragma unroll
    for (int j = 0; j < 4; ++j) mj[j] = SC4[(tr + 16*j)*(LDP/4) + s4];
#pragma unroll
    for (int k = 0; k < 4; ++k) xk[k] = SA4[(s4*4 + k)*(LDP/4) + tc];
#pragma unroll
    for (int j = 0; j < 4; ++j) {
      y1[j].x += mj[j].x*xk[0].x + mj[j].y*xk[1].x + mj[j].z*xk[2].x + mj[j].w*xk[3].x;
      y1[j].y += mj[j].x*xk[0].y + mj[j].y*xk[1].y + mj[j].z*xk[2].y + mj[j].w*xk[3].y;
      y1[j].z += mj[j].x*xk[0].z + mj[j].y*xk[1].z + mj[j].z*xk[2].z + mj[j].w*xk[3].z;
      y1[j].w += mj[j].x*xk[0].w + mj[j].y*xk[1].w + mj[j].z*xk[2].w + mj[j].w*xk[3].w;
    }
  }
  __syncthreads();
  // ---- load HT (flat [n*64+p]) into SC
  size_t hbase = (size_t)blk*4096;
  for (int i = tid; i < 4096; i += 256) SC[(i >> 6)*LDP + (i & 63)] = Hin[hbase + i];
  __syncthreads();
  // ---- Y2 = C H_in^T
  float4 y2[4];
#pragma unroll
  for (int j = 0; j < 4; ++j) y2[j] = make_float4(0.f,0.f,0.f,0.f);
#pragma unroll 2
  for (int n4 = 0; n4 < 16; ++n4) {
    float4 cj[4], hk[4];
#pragma unroll
    for (int j = 0; j < 4; ++j) cj[j] = SB4[(tr + 16*j)*(LDP/4) + n4];
#pragma unroll
    for (int k = 0; k < 4; ++k) hk[k] = SC4[(n4*4 + k)*(LDP/4) + tc];
#pragma unroll
    for (int j = 0; j < 4; ++j) {
      y2[j].x += cj[j].x*hk[0].x + cj[j].y*hk[1].x + cj[j].z*hk[2].x + cj[j].w*hk[3].x;
      y2[j].y += cj[j].x*hk[0].y + cj[j].y*hk[1].y + cj[j].z*hk[2].y + cj[j].w*hk[3].y;
      y2[j].z += cj[j].x*hk[0].z + cj[j].y*hk[1].z + cj[j].z*hk[2].z + cj[j].w*hk[3].z;
      y2[j].w += cj[j].x*hk[0].w + cj[j].y*hk[1].w + cj[j].z*hk[2].w + cj[j].w*hk[3].w;
    }
  }
#pragma unroll
  for (int j = 0; j < 4; ++j) {
    int t = tr + 16*j, tg = t0 + t;
    if (tg < LH) {
      float pr = pref[t];
      float4 o;
      o.x = y1[j].x + pr*y2[j].x;
      o.y = y1[j].y + pr*y2[j].y;
      o.z = y1[j].z + pr*y2[j].z;
      o.w = y1[j].w + pr*y2[j].w;
      *(float4*)(y + ((size_t)b*LH + tg)*DIN + hd*PDIM + tc*4) = o;
    }
  }
}

// ---------------------------------------------------------------- gate + rmsnorm + out_proj
// R7 structure (known-good). grid BATCH*256, block 256.
#define TR5 8
__global__ void __launch_bounds__(256) k_out(
    const float* __restrict__ y, const float* __restrict__ xbc,
    const float* __restrict__ zx, const float* __restrict__ Dh,
    const float* __restrict__ nw, const float* __restrict__ owT,
    float* __restrict__ h) {
  const int nblk_l = 256;
  int b = blockIdx.x / nblk_l;
  int l0 = (blockIdx.x % nblk_l) * TR5;
  int t = threadIdx.x;
  __shared__ __align__(16) float yv[TR5][DIN];
  __shared__ float part[4][TR5][DIM];          // 16 KB quarter partials
  __shared__ float red[TR5][4];
  __shared__ float rs[TR5];
  int c = t;
  int hd = c >> 6;
  float dcoef = Dh[hd];
  float nwc = nw[c];
  float v[TR5];
#pragma unroll
  for (int r = 0; r < TR5; ++r) {
    int l = l0 + r;
    float val = 0.f;
    if (l < LH) {
      size_t row = (size_t)b*LH + l;
      float ys = y[row*DIN + c];
      float xh = xbc[row*CONVD + c];
      float z  = zx[row*DPROJ + c];
      val = (ys + dcoef*xh) * siluf_(z);
    }
    v[r] = val;
  }
  int wave = t >> 6, lane = t & 63;
#pragma unroll
  for (int r = 0; r < TR5; ++r) {
    float sq = v[r]*v[r];
    for (int off = 32; off > 0; off >>= 1) sq += __shfl_down(sq, off);
    if (lane == 0) red[r][wave] = sq;
  }
  __syncthreads();
  if (t < TR5) {
    float sm = red[t][0]+red[t][1]+red[t][2]+red[t][3];
    rs[t] = rsqrtf(sm/(float)DIN + 1e-5f);
  }
  __syncthreads();
#pragma unroll
  for (int r = 0; r < TR5; ++r) yv[r][c] = v[r] * rs[r] * nwc;
  __syncthreads();
  int jp = t & 63, q = t >> 6;
  int j0 = jp*2;
  float acc[2][TR5];
#pragma unroll
  for (int jj = 0; jj < 2; ++jj)
#pragma unroll
    for (int r = 0; r < TR5; ++r) acc[jj][r] = 0.f;
  const float* wtb = owT + (size_t)q*64*DIM + j0;
#pragma unroll 2
  for (int k4 = 0; k4 < 16; ++k4) {
    float2 w0 = *(const float2*)(wtb + (k4*4+0)*DIM);   // coalesced (8B/lane)
    float2 w1 = *(const float2*)(wtb + (k4*4+1)*DIM);
    float2 w2_ = *(const float2*)(wtb + (k4*4+2)*DIM);
    float2 w3 = *(const float2*)(wtb + (k4*4+3)*DIM);
#pragma unroll
    for (int r = 0; r < TR5; ++r) {
      float4 hv = ((const float4*)&yv[r][q*64])[k4];  // broadcast
      acc[0][r] += w0.x*hv.x + w1.x*hv.y + w2_.x*hv.z + w3.x*hv.w;
      acc[1][r] += w0.y*hv.x + w1.y*hv.y + w2_.y*hv.z + w3.y*hv.w;
    }
  }
#pragma unroll
  for (int r = 0; r < TR5; ++r) {
    part[q][r][j0]   = acc[0][r];
    part[q][r][j0+1] = acc[1][r];
  }
  __syncthreads();
  if (t < DIM) {
#pragma unroll 2
    for (int r = 0; r < TR5; ++r) {
      int l = l0 + r;
      if (l < LH)
        h[((size_t)b*LH + l)*DIM + t] =
            part[0][r][t] + part[1][r][t] + part[2][r][t] + part[3][r][t];
    }
  }
}

// ---------------------------------------------------------------- final LN + head
__global__ void k_head(const float* __restrict__ h, const float* __restrict__ lnw,
                       const float* __restrict__ lnb, const float* __restrict__ hw,
                       const float* __restrict__ hb, float* __restrict__ out) {
  int b = blockIdx.x; int t = threadIdx.x;
  __shared__ float red[2];
  int wave = t >> 6, lane = t & 63;
  float v = h[((size_t)b*LH + LSEQ)*DIM + t];
  float s = v;
  for (int off = 32; off > 0; off >>= 1) s += __shfl_down(s, off);
  if (lane == 0) red[wave] = s;
  __syncthreads();
  float mean = (red[0]+red[1]) / (float)DIM;
  __syncthreads();
  float d = v - mean; float sq = d*d;
  for (int off = 32; off > 0; off >>= 1) sq += __shfl_down(sq, off);
  if (lane == 0) red[wave] = sq;
  __syncthreads();
  float var = (red[0]+red[1]) / (float)DIM;
  float cn = d*rsqrtf(var + 1e-5f)*lnw[t] + lnb[t];
  float dot = cn*hw[t];
  __syncthreads();
  for (int off = 32; off > 0; off >>= 1) dot += __shfl_down(dot, off);
  if (lane == 0) red[wave] = dot;
  __syncthreads();
  if (t == 0) out[b] = red[0]+red[1] + hb[0];
}

// ---------------------------------------------------------------- h -> d_out copy
__global__ void k_copy(const float* __restrict__ src, float* __restrict__ dst, long n4) {
  long i = (long)blockIdx.x*blockDim.x + threadIdx.x;
  if (i < n4) ((float4*)dst)[i] = ((const float4*)src)[i];
}

extern "C" void kernel_launch(void* const* d_in, const int* in_sizes, int n_in,
                              void* d_out, int out_size, void* d_ws, size_t ws_size,
                              hipStream_t stream) {
  const float* x     = (const float*)d_in[0];
  const float* w1    = (const float*)d_in[1];
  const float* b1    = (const float*)d_in[2];
  const float* w2    = (const float*)d_in[3];
  const float* b2    = (const float*)d_in[4];
  const float* cls   = (const float*)d_in[5];
  const float* inw   = (const float*)d_in[6];   // (4, 644, 128)
  const float* cw    = (const float*)d_in[7];   // (4, 384, 4)
  const float* cb    = (const float*)d_in[8];   // (4, 384)
  const float* dtb   = (const float*)d_in[9];   // (4, 4)
  const float* Alog  = (const float*)d_in[10];  // (4, 4)
  const float* Dh    = (const float*)d_in[11];  // (4, 4)
  const float* nw    = (const float*)d_in[12];  // (4, 256)
  const float* ow    = (const float*)d_in[13];  // (4, 128, 256)
  const float* lnw   = (const float*)d_in[14];
  const float* lnb   = (const float*)d_in[15];
  const float* hw    = (const float*)d_in[16];
  const float* hb    = (const float*)d_in[17];

  float* ws   = (float*)d_ws;
  float* hbuf = ws;                                   // 2,094,080
  float* zx   = hbuf + (size_t)BATCH*LH*DIM;          // 10,535,840
  float* xbc  = zx   + (size_t)BATCH*LH*DPROJ;        // 6,282,240
  float* ybuf = xbc  + (size_t)BATCH*LH*CONVD;        // 4,194,304 (G aliases ybuf)
  float* G    = ybuf;                                 //   (consumed before y written)
  float* Hin  = ybuf + 4194304;                       // 4,194,304
  float* dec  = Hin  + 4194304;                       // 1,024
  float* inwT = dec  + 1024;                          // 4*128*644 = 329,728
  float* owT  = inwT + 329728;                        // 4*256*128 = 131,072
  // total: 27,762,592 floats = 111.1 MiB

  k_transpose<<<dim3(2,11,4), 256, 0, stream>>>(inw, inwT, DPROJ, DIM);
  k_transpose<<<dim3(4,2,4),  256, 0, stream>>>(ow,  owT,  DIM, DIN);

  k_front<<<BATCH*64 + 1, 256, 0, stream>>>(x, w1, b1, w2, b2, cls, hbuf);

  for (int i = 0; i < DEPTH; ++i) {
    k_inproj<<<BATCH*128, 256, 0, stream>>>(
        hbuf, inwT + (size_t)i*DPROJ*DIM, dtb + i*NH, zx);
    {
      long total = (long)BATCH*LH*CONVD;
      k_conv<<<(int)((total + 255)/256), 256, 0, stream>>>(
          zx, cw + (size_t)i*CONVD*4, cb + (size_t)i*CONVD, xbc);
    }
    k_chunk_state<<<BATCH*NH*NCH, 256, 0, stream>>>(zx, xbc, Alog + i*NH, G, dec);
    k_combine<<<BATCH*NH*4, 256, 0, stream>>>(G, dec, Hin);
    k_chunk_out<<<BATCH*NH*NCH, 256, 0, stream>>>(zx, xbc, Alog + i*NH, Hin, ybuf);
    k_out<<<BATCH*256, 256, 0, stream>>>(
        ybuf, xbc, zx, Dh + i*NH, nw + (size_t)i*DIN, owT + (size_t)i*DIM*DIN, hbuf);
  }

  k_head<<<BATCH, 128, 0, stream>>>(hbuf, lnw, lnb, hw, hb, (float*)d_out);
  {
    long n4 = (long)BATCH*LH*DIM/4;
    k_copy<<<(int)((n4 + 255)/256), 256, 0, stream>>>(hbuf, (float*)d_out + 8, n4);
  }
}

// Round 11
// 808.977 us; speedup vs baseline: 1.5888x; 1.1722x over previous
//
#include <hip/hip_runtime.h>
#include <math.h>

// Shapes (fixed by setup_inputs)
#define BATCH 8
#define TSEQ 2048
#define CIN 3
#define WIN 5
#define LSEQ 2044          // T - WIN + 1
#define LH 2045            // LSEQ + 1 (cls token appended)
#define LHP 2048           // padded token rows for bf16 h buffer
#define DIM 128
#define DEPTH 4
#define DIN 256            // d_inner
#define NH 4               // heads
#define PDIM 64            // headdim
#define NSTATE 64          // d_state
#define CONVD 384          // d_inner + 2*d_state
#define DPROJ 644          // 2*d_inner + 2*d_state + nheads
#define DPROJP 656         // padded j rows for bf16 weight (41*16)
#define QC 64              // chunk length
#define NCH 32             // number of chunks
#define LDP 68             // padded LDS row stride
#define FTR 32             // tokens per k_front block

typedef __attribute__((ext_vector_type(8))) short bf16x8;
typedef __attribute__((ext_vector_type(4))) float f32x4;

__device__ __forceinline__ float sigmoidf_(float x){ return 1.f/(1.f+__expf(-x)); }
__device__ __forceinline__ float siluf_(float x){ return x*sigmoidf_(x); }
__device__ __forceinline__ unsigned short f2bf(float f){   // RNE fp32->bf16
  unsigned int u = __float_as_uint(f);
  return (unsigned short)((u + 0x7FFFu + ((u >> 16) & 1u)) >> 16);
}

// ---------------------------------------------------------------- weight transpose (ow only)
__global__ void __launch_bounds__(256) k_transpose(
    const float* __restrict__ src, float* __restrict__ dst, int R, int C) {
  __shared__ float tile[64][65];
  const float* s = src + (size_t)blockIdx.z*R*C;
  float* d = dst + (size_t)blockIdx.z*R*C;
  int r0 = blockIdx.y*64, c0 = blockIdx.x*64;
  int tx = threadIdx.x & 63, ty = threadIdx.x >> 6;
  for (int rr = ty; rr < 64; rr += 4) {
    int r = r0 + rr, c = c0 + tx;
    if (r < R && c < C) tile[rr][tx] = s[(size_t)r*C + c];
  }
  __syncthreads();
  for (int cc = ty; cc < 64; cc += 4) {
    int c = c0 + cc, r = r0 + tx;
    if (c < C && r < R) d[(size_t)c*R + r] = tile[tx][cc];
  }
}

// ---------------------------------------------------------------- fp32 -> bf16 casts
// h: [b][LH][128] fp32 -> [b][2048][128] bf16 (pad rows zero)
__global__ void __launch_bounds__(256) k_cast_h(
    const float* __restrict__ h, unsigned short* __restrict__ hB) {
  size_t gid = (size_t)blockIdx.x*256 + threadIdx.x;   // one float4 per thread
  size_t e = gid*4;
  if (e >= (size_t)BATCH*LHP*DIM) return;
  int b = (int)(e / (LHP*DIM));
  int rem = (int)(e - (size_t)b*LHP*DIM);
  int row = rem >> 7, col = rem & 127;
  float4 v = make_float4(0.f,0.f,0.f,0.f);
  if (row < LH) v = *(const float4*)(h + ((size_t)b*LH + row)*DIM + col);
  unsigned short o[4] = { f2bf(v.x), f2bf(v.y), f2bf(v.z), f2bf(v.w) };
  *(uint2*)(hB + e) = *(const uint2*)o;
}

// inw: [4][644][128] fp32 -> [4][656][128] bf16 (pad rows zero)
__global__ void __launch_bounds__(256) k_cast_w(
    const float* __restrict__ w, unsigned short* __restrict__ wB) {
  size_t gid = (size_t)blockIdx.x*256 + threadIdx.x;
  size_t e = gid*4;
  if (e >= (size_t)DEPTH*DPROJP*DIM) return;
  int ly = (int)(e / (DPROJP*DIM));
  int rem = (int)(e - (size_t)ly*DPROJP*DIM);
  int row = rem >> 7, col = rem & 127;
  float4 v = make_float4(0.f,0.f,0.f,0.f);
  if (row < DPROJ) v = *(const float4*)(w + ((size_t)ly*DPROJ + row)*DIM + col);
  unsigned short o[4] = { f2bf(v.x), f2bf(v.y), f2bf(v.z), f2bf(v.w) };
  *(uint2*)(wB + e) = *(const uint2*)o;
}

// ---------------------------------------------------------------- front MLP
__global__ void __launch_bounds__(256) k_front(
    const float* __restrict__ x, const float* __restrict__ w1,
    const float* __restrict__ b1, const float* __restrict__ w2,
    const float* __restrict__ b2, const float* __restrict__ cls,
    float* __restrict__ h) {
  int t = threadIdx.x;
  if (blockIdx.x == BATCH*64) {              // cls rows
    if (t < DIM) {
      float cv = cls[t];
      for (int b = 0; b < BATCH; ++b) h[((size_t)b*LH + LSEQ)*DIM + t] = cv;
    }
    return;
  }
  int b = blockIdx.x >> 6;
  int c0 = (blockIdx.x & 63) * FTR;
  __shared__ float xs[(FTR+4)*CIN];
  __shared__ float w1s[DIM*17];
  __shared__ __align__(16) float h1s[FTR][DIM];
  __shared__ float part[FTR][DIM][2];
  for (int i = t; i < (FTR+4)*CIN; i += 256) {
    int row = c0 + i/3, ch = i - (i/3)*3;
    xs[i] = (row < TSEQ) ? x[(size_t)b*TSEQ*CIN + (size_t)row*CIN + ch] : 0.f;
  }
  for (int i = t; i < DIM*15; i += 256) {
    int j = i/15, k = i - j*15;
    w1s[j*17+k] = w1[i];
  }
  __syncthreads();
  {
    int j = t & 127, rh = t >> 7;
    float bias = b1[j];
    const float* wr = &w1s[j*17];
    for (int r = rh*16; r < rh*16+16; ++r) {
      float a = bias;
#pragma unroll
      for (int k = 0; k < 15; ++k) a += xs[r*3+k]*wr[k];
      h1s[r][j] = 0.5f*a*(1.f + erff(a*0.70710678118654752f));  // exact gelu
    }
  }
  __syncthreads();
  {
    int j = t & 127, hf = t >> 7;
    float4 wv[16];
    const float4* w2r = (const float4*)(w2 + (size_t)j*DIM + hf*64);
#pragma unroll
    for (int k4 = 0; k4 < 16; ++k4) wv[k4] = w2r[k4];
#pragma unroll 2
    for (int r = 0; r < FTR; ++r) {
      const float4* hr = (const float4*)&h1s[r][hf*64];
      float acc = 0.f;
#pragma unroll
      for (int k4 = 0; k4 < 16; ++k4) {
        float4 hv = hr[k4];
        acc += wv[k4].x*hv.x + wv[k4].y*hv.y + wv[k4].z*hv.z + wv[k4].w*hv.w;
      }
      part[r][j][hf] = acc;
    }
  }
  __syncthreads();
  if (t < DIM) {
    float bias = b2[t];
    for (int r = 0; r < FTR; ++r) {
      int l = c0 + r;
      if (l < LSEQ) h[((size_t)b*LH + l)*DIM + t] = part[r][t][0] + part[r][t][1] + bias;
    }
  }
}

// ---------------------------------------------------------------- in_proj via bf16 MFMA
// grid: BATCH*32 blocks, 256 threads = 4 waves; wave w owns tokens l0 = lb*64+w*16.
// C[tok][j] = sum_k h[tok][k] * W[j][k]. A-frag: h[m=lane&15][k=q*8+i] (m120 layout);
// B-frag: W[n=lane&15][k=q*8+i] (original [j][k] layout — no transpose!);
// D: col=lane&15 -> j, row=q*4+reg -> token (m89 layout).
__global__ void __launch_bounds__(256) k_inproj_mfma(
    const unsigned short* __restrict__ hB, const unsigned short* __restrict__ wB,
    const float* __restrict__ dtb, float* __restrict__ zx) {
  int b = blockIdx.x >> 5;
  int lb = blockIdx.x & 31;
  int wv = threadIdx.x >> 6, lane = threadIdx.x & 63;
  int l0 = lb*64 + wv*16;
  int m = lane & 15, q = lane >> 4;
  const unsigned short* hrow = hB + ((size_t)b*LHP + (l0 + m))*DIM + q*8;
  bf16x8 afr[4];
#pragma unroll
  for (int kb = 0; kb < 4; ++kb) afr[kb] = *(const bf16x8*)(hrow + kb*32);
#pragma unroll 2
  for (int jt = 0; jt < 41; ++jt) {
    int j0 = jt*16;
    const unsigned short* wrow = wB + (size_t)(j0 + m)*DIM + q*8;
    bf16x8 bfr[4];
#pragma unroll
    for (int kb = 0; kb < 4; ++kb) bfr[kb] = *(const bf16x8*)(wrow + kb*32);
    f32x4 acc = {0.f, 0.f, 0.f, 0.f};
#pragma unroll
    for (int kb = 0; kb < 4; ++kb)
      acc = __builtin_amdgcn_mfma_f32_16x16x32_bf16(afr[kb], bfr[kb], acc, 0, 0, 0);
    int jj = j0 + m;                        // D col = lane&15
    if (jj < DPROJ) {
      bool isdt = (jj >= 640);
      float bias = isdt ? dtb[jj - 640] : 0.f;
#pragma unroll
      for (int r = 0; r < 4; ++r) {
        int tok = l0 + q*4 + r;             // D row = q*4 + reg
        if (tok < LH) {
          float v = acc[r];
          if (isdt) { v += bias; v = (v > 20.f) ? v : log1pf(__expf(v)); }
          zx[((size_t)b*LH + tok)*DPROJ + jj] = v;
        }
      }
    }
  }
}

// ---------------------------------------------------------------- causal dwconv + silu
// (R9 lesson: materialize once — fusing into consumers recomputes conv+exp 2-3x.)
__global__ void k_conv(const float* __restrict__ zx, const float* __restrict__ cw,
                       const float* __restrict__ cb, float* __restrict__ xbc) {
  size_t idx = (size_t)blockIdx.x*blockDim.x + threadIdx.x;
  const size_t total = (size_t)BATCH*LH*CONVD;
  if (idx >= total) return;
  int c = (int)(idx % CONVD);
  size_t bl = idx / CONVD;
  int l = (int)(bl % LH); int b = (int)(bl / LH);
  float acc = cb[c];
#pragma unroll
  for (int k = 0; k < 4; ++k) {
    int tin = l - 3 + k;
    if (tin >= 0) acc += zx[((size_t)b*LH + tin)*DPROJ + DIN + c] * cw[c*4 + k];
  }
  xbc[idx] = siluf_(acc);
}

// ---------------------------------------------------------------- chunked SSD, phase A
__global__ void __launch_bounds__(256) k_chunk_state(
    const float* __restrict__ zx, const float* __restrict__ xbc,
    const float* __restrict__ A_log, float* __restrict__ G, float* __restrict__ dec) {
  int blk = blockIdx.x;
  int c = blk & (NCH-1), hd = (blk >> 5) & 3, b = blk >> 7;
  int t0 = c*QC;
  int tid = threadIdx.x;
  float A = -__expf(A_log[hd]);
  __shared__ float xs[QC*PDIM];
  __shared__ float Bs[QC*NSTATE];
  __shared__ float coef[QC];
  if (tid < 64) {
    int tg = t0 + tid;
    float dtv = (tg < LH) ? zx[((size_t)b*LH + tg)*DPROJ + 640 + hd] : 0.f;
    float s = dtv;
#pragma unroll
    for (int off = 1; off < 64; off <<= 1) {
      float u = __shfl_up(s, off);
      if (tid >= off) s += u;
    }
    float cq = __shfl(s, 63);
    coef[tid] = __expf(A*(cq - s)) * dtv;
    if (tid == 63) dec[blk] = __expf(A * s);
  }
  for (int i = tid; i < QC*64; i += 256) {
    int s = i >> 6, j = i & 63;
    int tg = t0 + s;
    float xv = 0.f, bv = 0.f;
    if (tg < LH) {
      size_t row = ((size_t)b*LH + tg)*CONVD;
      xv = xbc[row + hd*PDIM + j];
      bv = xbc[row + DIN + j];
    }
    xs[i] = xv; Bs[i] = bv;
  }
  __syncthreads();
  int n = tid >> 2, q = tid & 3;
  float4 acc[4];
#pragma unroll
  for (int i4 = 0; i4 < 4; ++i4) acc[i4] = make_float4(0.f,0.f,0.f,0.f);
  const float4* xs4 = (const float4*)xs;
#pragma unroll 4
  for (int s = 0; s < QC; ++s) {            // capped unroll: keep VGPRs < spill
    float cb_ = coef[s] * Bs[s*64 + n];
#pragma unroll
    for (int i4 = 0; i4 < 4; ++i4) {
      float4 xv = xs4[s*16 + q*4 + i4];
      acc[i4].x += cb_*xv.x; acc[i4].y += cb_*xv.y;
      acc[i4].z += cb_*xv.z; acc[i4].w += cb_*xv.w;
    }
  }
  float4* gp = (float4*)(G + (size_t)blk*4096 + n*64 + q*16);
#pragma unroll
  for (int i4 = 0; i4 < 4; ++i4) gp[i4] = acc[i4];
}

// ---------------------------------------------------------------- phase B: inter-chunk
__global__ void __launch_bounds__(256) k_combine(
    const float* __restrict__ G, const float* __restrict__ dec, float* __restrict__ Hin) {
  int bh = blockIdx.x >> 2, esp = blockIdx.x & 3;
  int e = esp*1024 + threadIdx.x*4;
  size_t base0 = (size_t)bh*NCH*4096 + e;
  float4 H = make_float4(0.f,0.f,0.f,0.f);
  float4 g = *(const float4*)(G + base0);
  float d = dec[bh*NCH];
  for (int c = 0; c < NCH; ++c) {
    float4 gn = make_float4(0.f,0.f,0.f,0.f); float dn = 0.f;
    if (c + 1 < NCH) {
      gn = *(const float4*)(G + base0 + (size_t)(c+1)*4096);
      dn = dec[bh*NCH + c + 1];
    }
    *(float4*)(Hin + base0 + (size_t)c*4096) = H;   // carry-in for chunk c
    H.x = H.x*d + g.x; H.y = H.y*d + g.y; H.z = H.z*d + g.z; H.w = H.w*d + g.w;
    g = gn; d = dn;
  }
}

// ---------------------------------------------------------------- phase C: chunk output
__global__ void __launch_bounds__(256) k_chunk_out(
    const float* __restrict__ zx, const float* __restrict__ xbc,
    const float* __restrict__ A_log, const float* __restrict__ Hin,
    float* __restrict__ y) {
  int blk = blockIdx.x;
  int c = blk & (NCH-1), hd = (blk >> 5) & 3, b = blk >> 7;
  int t0 = c*QC;
  int tid = threadIdx.x;
  int tr = tid >> 4, tc = tid & 15;
  float A = -__expf(A_log[hd]);
  __shared__ __align__(16) float SA[QC*LDP];
  __shared__ __align__(16) float SB[QC*LDP];
  __shared__ __align__(16) float SC[QC*LDP];
  __shared__ float cum[QC], dts[QC], pref[QC];
  if (tid < 64) {
    int tg = t0 + tid;
    float dtv = (tg < LH) ? zx[((size_t)b*LH + tg)*DPROJ + 640 + hd] : 0.f;
    float s = dtv;
#pragma unroll
    for (int off = 1; off < 64; off <<= 1) {
      float u = __shfl_up(s, off);
      if (tid >= off) s += u;
    }
    dts[tid] = dtv; cum[tid] = s; pref[tid] = __expf(A*s);
  }
  for (int i = tid; i < QC*64; i += 256) {
    int s = i >> 6, j = i & 63;
    int tg = t0 + s;
    float bv = 0.f, cv = 0.f;
    if (tg < LH) {
      size_t row = ((size_t)b*LH + tg)*CONVD;
      bv = xbc[row + DIN + j];
      cv = xbc[row + DIN + NSTATE + j];
    }
    SA[s*LDP + j] = bv; SB[s*LDP + j] = cv;
  }
  __syncthreads();
  // ---- S = C B^T
  float S[4][4];
#pragma unroll
  for (int j = 0; j < 4; ++j)
#pragma unroll
    for (int i = 0; i < 4; ++i) S[j][i] = 0.f;
  const float4* SA4 = (const float4*)SA;
  const float4* SB4 = (const float4*)SB;
#pragma unroll 2
  for (int n4 = 0; n4 < 16; ++n4) {
    float4 cv[4], bv[4];
#pragma unroll
    for (int j = 0; j < 4; ++j) cv[j] = SB4[(tr + 16*j)*(LDP/4) + n4];
#pragma unroll
    for (int i = 0; i < 4; ++i) bv[i] = SA4[(tc + 16*i)*(LDP/4) + n4];
#pragma unroll
    for (int j = 0; j < 4; ++j)
#pragma unroll
      for (int i = 0; i < 4; ++i)
        S[j][i] += cv[j].x*bv[i].x + cv[j].y*bv[i].y + cv[j].z*bv[i].z + cv[j].w*bv[i].w;
  }
  __syncthreads();
  // ---- masked decay -> M in SC; reload X into SA
#pragma unroll
  for (int j = 0; j < 4; ++j) {
    int t = tr + 16*j;
#pragma unroll
    for (int i = 0; i < 4; ++i) {
      int s = tc + 16*i;
      float m = 0.f;
      if (s <= t) m = S[j][i] * __expf(A*(cum[t] - cum[s])) * dts[s];
      SC[t*LDP + s] = m;
    }
  }
  for (int i = tid; i < QC*64; i += 256) {
    int s = i >> 6, j = i & 63;
    int tg = t0 + s;
    SA[s*LDP + j] = (tg < LH) ? xbc[((size_t)b*LH + tg)*CONVD + hd*PDIM + j] : 0.f;
  }
  __syncthreads();
  // ---- Y1 = M X
  float4 y1[4];
#pragma unroll
  for (int j = 0; j < 4; ++j) y1[j] = make_float4(0.f,0.f,0.f,0.f);
  const float4* SC4 = (const float4*)SC;
#pragma unroll 2
  for (int s4 = 0; s4 < 16; ++s4) {
    float4 mj[4], xk[4];
#pragma unroll
    for (int j = 0; j < 4; ++j) mj[j] = SC4[(tr + 16*j)*(LDP/4) + s4];
#pragma unroll
    for (int k = 0; k < 4; ++k) xk[k] = SA4[(s4*4 + k)*(LDP/4) + tc];
#pragma unroll
    for (int j = 0; j < 4; ++j) {
      y1[j].x += mj[j].x*xk[0].x + mj[j].y*xk[1].x + mj[j].z*xk[2].x + mj[j].w*xk[3].x;
      y1[j].y += mj[j].x*xk[0].y + mj[j].y*xk[1].y + mj[j].z*xk[2].y + mj[j].w*xk[3].y;
      y1[j].z += mj[j].x*xk[0].z + mj[j].y*xk[1].z + mj[j].z*xk[2].z + mj[j].w*xk[3].z;
      y1[j].w += mj[j].x*xk[0].w + mj[j].y*xk[1].w + mj[j].z*xk[2].w + mj[j].w*xk[3].w;
    }
  }
  __syncthreads();
  size_t hbase = (size_t)blk*4096;
  for (int i = tid; i < 4096; i += 256) SC[(i >> 6)*LDP + (i & 63)] = Hin[hbase + i];
  __syncthreads();
  // ---- Y2 = C H_in^T
  float4 y2[4];
#pragma unroll
  for (int j = 0; j < 4; ++j) y2[j] = make_float4(0.f,0.f,0.f,0.f);
#pragma unroll 2
  for (int n4 = 0; n4 < 16; ++n4) {
    float4 cj[4], hk[4];
#pragma unroll
    for (int j = 0; j < 4; ++j) cj[j] = SB4[(tr + 16*j)*(LDP/4) + n4];
#pragma unroll
    for (int k = 0; k < 4; ++k) hk[k] = SC4[(n4*4 + k)*(LDP/4) + tc];
#pragma unroll
    for (int j = 0; j < 4; ++j) {
      y2[j].x += cj[j].x*hk[0].x + cj[j].y*hk[1].x + cj[j].z*hk[2].x + cj[j].w*hk[3].x;
      y2[j].y += cj[j].x*hk[0].y + cj[j].y*hk[1].y + cj[j].z*hk[2].y + cj[j].w*hk[3].y;
      y2[j].z += cj[j].x*hk[0].z + cj[j].y*hk[1].z + cj[j].z*hk[2].z + cj[j].w*hk[3].z;
      y2[j].w += cj[j].x*hk[0].w + cj[j].y*hk[1].w + cj[j].z*hk[2].w + cj[j].w*hk[3].w;
    }
  }
#pragma unroll
  for (int j = 0; j < 4; ++j) {
    int t = tr + 16*j, tg = t0 + t;
    if (tg < LH) {
      float pr = pref[t];
      float4 o;
      o.x = y1[j].x + pr*y2[j].x;
      o.y = y1[j].y + pr*y2[j].y;
      o.z = y1[j].z + pr*y2[j].z;
      o.w = y1[j].w + pr*y2[j].w;
      *(float4*)(y + ((size_t)b*LH + tg)*DIN + hd*PDIM + tc*4) = o;
    }
  }
}

// ---------------------------------------------------------------- gate + rmsnorm + out_proj
#define TR5 8
__global__ void __launch_bounds__(256) k_out(
    const float* __restrict__ y, const float* __restrict__ xbc,
    const float* __restrict__ zx, const float* __restrict__ Dh,
    const float* __restrict__ nw, const float* __restrict__ owT,
    float* __restrict__ h) {
  const int nblk_l = 256;
  int b = blockIdx.x / nblk_l;
  int l0 = (blockIdx.x % nblk_l) * TR5;
  int t = threadIdx.x;
  __shared__ __align__(16) float yv[TR5][DIN];
  __shared__ float part[4][TR5][DIM];
  __shared__ float red[TR5][4];
  __shared__ float rs[TR5];
  int c = t;
  int hd = c >> 6;
  float dcoef = Dh[hd];
  float nwc = nw[c];
  float v[TR5];
#pragma unroll
  for (int r = 0; r < TR5; ++r) {
    int l = l0 + r;
    float val = 0.f;
    if (l < LH) {
      size_t row = (size_t)b*LH + l;
      float ys = y[row*DIN + c];
      float xh = xbc[row*CONVD + c];
      float z  = zx[row*DPROJ + c];
      val = (ys + dcoef*xh) * siluf_(z);
    }
    v[r] = val;
  }
  int wave = t >> 6, lane = t & 63;
#pragma unroll
  for (int r = 0; r < TR5; ++r) {
    float sq = v[r]*v[r];
    for (int off = 32; off > 0; off >>= 1) sq += __shfl_down(sq, off);
    if (lane == 0) red[r][wave] = sq;
  }
  __syncthreads();
  if (t < TR5) {
    float sm = red[t][0]+red[t][1]+red[t][2]+red[t][3];
    rs[t] = rsqrtf(sm/(float)DIN + 1e-5f);
  }
  __syncthreads();
#pragma unroll
  for (int r = 0; r < TR5; ++r) yv[r][c] = v[r] * rs[r] * nwc;
  __syncthreads();
  int jp = t & 63, q = t >> 6;
  int j0 = jp*2;
  float acc[2][TR5];
#pragma unroll
  for (int jj = 0; jj < 2; ++jj)
#pragma unroll
    for (int r = 0; r < TR5; ++r) acc[jj][r] = 0.f;
  const float* wtb = owT + (size_t)q*64*DIM + j0;
#pragma unroll 2
  for (int k4 = 0; k4 < 16; ++k4) {
    float2 w0 = *(const float2*)(wtb + (k4*4+0)*DIM);
    float2 w1 = *(const float2*)(wtb + (k4*4+1)*DIM);
    float2 w2_ = *(const float2*)(wtb + (k4*4+2)*DIM);
    float2 w3 = *(const float2*)(wtb + (k4*4+3)*DIM);
#pragma unroll
    for (int r = 0; r < TR5; ++r) {
      float4 hv = ((const float4*)&yv[r][q*64])[k4];
      acc[0][r] += w0.x*hv.x + w1.x*hv.y + w2_.x*hv.z + w3.x*hv.w;
      acc[1][r] += w0.y*hv.x + w1.y*hv.y + w2_.y*hv.z + w3.y*hv.w;
    }
  }
#pragma unroll
  for (int r = 0; r < TR5; ++r) {
    part[q][r][j0]   = acc[0][r];
    part[q][r][j0+1] = acc[1][r];
  }
  __syncthreads();
  if (t < DIM) {
#pragma unroll 2
    for (int r = 0; r < TR5; ++r) {
      int l = l0 + r;
      if (l < LH)
        h[((size_t)b*LH + l)*DIM + t] =
            part[0][r][t] + part[1][r][t] + part[2][r][t] + part[3][r][t];
    }
  }
}

// ---------------------------------------------------------------- final LN + head
__global__ void k_head(const float* __restrict__ h, const float* __restrict__ lnw,
                       const float* __restrict__ lnb, const float* __restrict__ hw,
                       const float* __restrict__ hb, float* __restrict__ out) {
  int b = blockIdx.x; int t = threadIdx.x;
  __shared__ float red[2];
  int wave = t >> 6, lane = t & 63;
  float v = h[((size_t)b*LH + LSEQ)*DIM + t];
  float s = v;
  for (int off = 32; off > 0; off >>= 1) s += __shfl_down(s, off);
  if (lane == 0) red[wave] = s;
  __syncthreads();
  float mean = (red[0]+red[1]) / (float)DIM;
  __syncthreads();
  float d = v - mean; float sq = d*d;
  for (int off = 32; off > 0; off >>= 1) sq += __shfl_down(sq, off);
  if (lane == 0) red[wave] = sq;
  __syncthreads();
  float var = (red[0]+red[1]) / (float)DIM;
  float cn = d*rsqrtf(var + 1e-5f)*lnw[t] + lnb[t];
  float dot = cn*hw[t];
  __syncthreads();
  for (int off = 32; off > 0; off >>= 1) dot += __shfl_down(dot, off);
  if (lane == 0) red[wave] = dot;
  __syncthreads();
  if (t == 0) out[b] = red[0]+red[1] + hb[0];
}

// ---------------------------------------------------------------- h -> d_out copy
__global__ void k_copy(const float* __restrict__ src, float* __restrict__ dst, long n4) {
  long i = (long)blockIdx.x*blockDim.x + threadIdx.x;
  if (i < n4) ((float4*)dst)[i] = ((const float4*)src)[i];
}

extern "C" void kernel_launch(void* const* d_in, const int* in_sizes, int n_in,
                              void* d_out, int out_size, void* d_ws, size_t ws_size,
                              hipStream_t stream) {
  const float* x     = (const float*)d_in[0];
  const float* w1    = (const float*)d_in[1];
  const float* b1    = (const float*)d_in[2];
  const float* w2    = (const float*)d_in[3];
  const float* b2    = (const float*)d_in[4];
  const float* cls   = (const float*)d_in[5];
  const float* inw   = (const float*)d_in[6];   // (4, 644, 128)
  const float* cw    = (const float*)d_in[7];   // (4, 384, 4)
  const float* cb    = (const float*)d_in[8];   // (4, 384)
  const float* dtb   = (const float*)d_in[9];   // (4, 4)
  const float* Alog  = (const float*)d_in[10];  // (4, 4)
  const float* Dh    = (const float*)d_in[11];  // (4, 4)
  const float* nw    = (const float*)d_in[12];  // (4, 256)
  const float* ow    = (const float*)d_in[13];  // (4, 128, 256)
  const float* lnw   = (const float*)d_in[14];
  const float* lnb   = (const float*)d_in[15];
  const float* hw    = (const float*)d_in[16];
  const float* hb    = (const float*)d_in[17];

  float* ws   = (float*)d_ws;
  float* hbuf = ws;                                   // 2,094,080
  float* zx   = hbuf + (size_t)BATCH*LH*DIM;          // 10,535,840
  float* xbc  = zx   + (size_t)BATCH*LH*DPROJ;        // 6,282,240
  float* ybuf = xbc  + (size_t)BATCH*LH*CONVD;        // 4,194,304 (G aliases ybuf)
  float* G    = ybuf;
  float* Hin  = ybuf + 4194304;                       // 4,194,304
  float* dec  = Hin  + 4194304;                       // 1,024
  float* owT  = dec  + 1024;                          // 4*256*128 = 131,072
  unsigned short* hB = (unsigned short*)(owT + 131072);      // 8*2048*128 u16 = 1,048,576 f
  unsigned short* wB = hB + (size_t)BATCH*LHP*DIM;           // 4*656*128 u16 = 167,936 f
  // total ~28.65M floats = 114.6 MiB

  k_cast_w<<<(DEPTH*DPROJP*DIM/4 + 255)/256, 256, 0, stream>>>(inw, wB);
  k_transpose<<<dim3(4,2,4), 256, 0, stream>>>(ow, owT, DIM, DIN);

  k_front<<<BATCH*64 + 1, 256, 0, stream>>>(x, w1, b1, w2, b2, cls, hbuf);

  for (int i = 0; i < DEPTH; ++i) {
    k_cast_h<<<(BATCH*LHP*DIM/4 + 255)/256, 256, 0, stream>>>(hbuf, hB);
    k_inproj_mfma<<<BATCH*32, 256, 0, stream>>>(
        hB, wB + (size_t)i*DPROJP*DIM, dtb + i*NH, zx);
    {
      long total = (long)BATCH*LH*CONVD;
      k_conv<<<(int)((total + 255)/256), 256, 0, stream>>>(
          zx, cw + (size_t)i*CONVD*4, cb + (size_t)i*CONVD, xbc);
    }
    k_chunk_state<<<BATCH*NH*NCH, 256, 0, stream>>>(zx, xbc, Alog + i*NH, G, dec);
    k_combine<<<BATCH*NH*4, 256, 0, stream>>>(G, dec, Hin);
    k_chunk_out<<<BATCH*NH*NCH, 256, 0, stream>>>(zx, xbc, Alog + i*NH, Hin, ybuf);
    k_out<<<BATCH*256, 256, 0, stream>>>(
        ybuf, xbc, zx, Dh + i*NH, nw + (size_t)i*DIN, owT + (size_t)i*DIM*DIN, hbuf);
  }

  k_head<<<BATCH, 128, 0, stream>>>(hbuf, lnw, lnb, hw, hb, (float*)d_out);
  {
    long n4 = (long)BATCH*LH*DIM/4;
    k_copy<<<(int)((n4 + 255)/256), 256, 0, stream>>>(hbuf, (float*)d_out + 8, n4);
  }
}